// Round 10
// baseline (222.623 us; speedup 1.0000x reference)
//
#include <hip/hip_runtime.h>
#include <hip/hip_bf16.h>
#include <cstdint>
#include <cstddef>

#define B_SZ 4096

typedef __attribute__((ext_vector_type(4))) float f32x4;
typedef __attribute__((ext_vector_type(8))) short sv8;
typedef __attribute__((ext_vector_type(8))) __bf16 bfv8;

// Pre-packed parameters (written by ncfg_prep, read by ncfg_neigh)
__device__ __align__(16) short g_wf[2][8][64][8];  // [mat][nt*2+kh][lane][j]
__device__ float g_bsum[64];                       // b_ih + b_hh
__device__ float g_reldot[32];                     // trf[r] . attn_w[64:128]

static __device__ __forceinline__ short f2bf(float x) {
  union { float f; unsigned u; } v; v.f = x;
  unsigned r = v.u + 0x7fffu + ((v.u >> 16) & 1u);
  return (short)(r >> 16);
}
static __device__ __forceinline__ short f2bfc(float x) {
  return (short)__builtin_bit_cast(unsigned short, __float2bfloat16(x));
}

static __device__ __forceinline__ f32x4 MFMA(sv8 a, sv8 b, f32x4 c) {
  return __builtin_amdgcn_mfma_f32_16x16x32_bf16(
      __builtin_bit_cast(bfv8, a), __builtin_bit_cast(bfv8, b), c, 0, 0, 0);
}

static __device__ __forceinline__ float fast_sigmoid(float x) {
  return __builtin_amdgcn_rcpf(1.f + __expf(-x));
}
static __device__ __forceinline__ float fast_tanh(float x) {
  const float e = __expf(2.f * x);
  return 1.f - 2.f * __builtin_amdgcn_rcpf(e + 1.f);
}
static __device__ __forceinline__ float dot4(f32x4 a, f32x4 b) {
  return a.x * b.x + a.y * b.y + a.z * b.z + a.w * b.w;
}
static __device__ __forceinline__ sv8 pack8(f32x4 a, f32x4 b) {
  sv8 f;
  f[0] = f2bfc(a.x); f[1] = f2bfc(a.y); f[2] = f2bfc(a.z); f[3] = f2bfc(a.w);
  f[4] = f2bfc(b.x); f[5] = f2bfc(b.y); f[6] = f2bfc(b.z); f[7] = f2bfc(b.w);
  return f;
}

// ---------------------------------------------------------------------------
// Prep: pack W into bf16 MFMA fragments, fold biases, rel dots.
// ---------------------------------------------------------------------------
__global__ __launch_bounds__(256) void ncfg_prep(
    const float* __restrict__ W_ih, const float* __restrict__ W_hh,
    const float* __restrict__ b_ih, const float* __restrict__ b_hh,
    const float* __restrict__ trf, const float* __restrict__ attn_w) {
  const int t = threadIdx.x;
  for (int q = t; q < 1024; q += 256) {
    const int m = q >> 9, f = (q >> 6) & 7, ln = q & 63;
    const int nt = f >> 1, kh = f & 1, fr = ln & 15, fg = ln >> 4;
    const float* W = m ? W_hh : W_ih;
    const float* src = W + (nt * 16 + fr) * 64 + kh * 32 + fg * 8;
    short* dst = &g_wf[m][f][ln][0];
    #pragma unroll
    for (int j = 0; j < 8; ++j) dst[j] = f2bf(src[j]);
  }
  if (t < 64) g_bsum[t] = b_ih[t] + b_hh[t];
  if (t < 32) {
    float s = 0.f;
    #pragma unroll 8
    for (int c = 0; c < 64; ++c) s += trf[t * 64 + c] * attn_w[64 + c];
    g_reldot[t] = s;
  }
}

// ---------------------------------------------------------------------------
// Phase A: persistent blocks (1024); each wave grid-strides over 8
// independent 16-row chunks, software-pipelined (gathers k+1 and idx k+2 in
// flight during compute of k). No in-loop barriers; per-chunk partial o and
// sum(e) go to global; head combines.
// ---------------------------------------------------------------------------
__global__ __launch_bounds__(256, 4) void ncfg_neigh(
    const int* __restrict__ heads, const int* __restrict__ rels,
    const int* __restrict__ tails, const float* __restrict__ emb,
    const float* __restrict__ attn_w, const float* __restrict__ attn_b,
    float* __restrict__ owp, float* __restrict__ sep) {
  const int t = threadIdx.x;
  const int lane = t & 63;
  const int w = t >> 6;
  const int fr = lane & 15;
  const int fg = lane >> 4;
  const int c0 = fg * 8;

  __shared__ __align__(16) short wlds[2][8][64][8];  // 16 KB W fragments
  __shared__ __align__(16) float awlds[192];         // attn vector
  __shared__ float rlds[32];                         // reldot
  __shared__ __align__(16) short h1s[4][16 * 72];    // 9 KB per-wave h1

  // stage weights / attn / reldot ONCE per persistent block
  {
    const f32x4* s1 = (const f32x4*)&g_wf[0][0][0][0];
    f32x4* d1 = (f32x4*)&wlds[0][0][0][0];
    #pragma unroll
    for (int i = 0; i < 4; ++i) d1[t + i * 256] = s1[t + i * 256];
    if (t < 48) ((f32x4*)awlds)[t] = ((const f32x4*)attn_w)[t];
    if (t < 8) ((f32x4*)rlds)[t] = ((const f32x4*)g_reldot)[t];
  }
  float bsum[4];
  #pragma unroll
  for (int nt = 0; nt < 4; ++nt) bsum[nt] = g_bsum[nt * 16 + fr];
  const float ab0 = attn_b[0];
  __syncthreads();  // the only barrier

  const int gwid = blockIdx.x * 4 + w;  // 0..4095
  const int cb = gwid * 8;              // 8 chunks per wave

  // pipeline state
  int hiA[2], tiA[2], riA[2];
  hiA[0] = heads[(size_t)cb * 16 + fr];
  tiA[0] = tails[(size_t)cb * 16 + fr];
  riA[0] = rels[(size_t)cb * 16 + fr];
  hiA[1] = heads[(size_t)(cb + 1) * 16 + fr];
  tiA[1] = tails[(size_t)(cb + 1) * 16 + fr];
  riA[1] = rels[(size_t)(cb + 1) * 16 + fr];

  f32x4 gh0, gh1, gh2, gh3, gt0, gt1, gt2, gt3;
#define LOADG(hh, tt)                                                 \
  {                                                                   \
    const float* hr_ = emb + (size_t)(hh)*64;                         \
    const float* tr_ = emb + (size_t)(tt)*64;                         \
    gh0 = *(const f32x4*)(hr_ + c0);                                  \
    gh1 = *(const f32x4*)(hr_ + c0 + 4);                              \
    gh2 = *(const f32x4*)(hr_ + 32 + c0);                             \
    gh3 = *(const f32x4*)(hr_ + 32 + c0 + 4);                         \
    gt0 = *(const f32x4*)(tr_ + c0);                                  \
    gt1 = *(const f32x4*)(tr_ + c0 + 4);                              \
    gt2 = *(const f32x4*)(tr_ + 32 + c0);                             \
    gt3 = *(const f32x4*)(tr_ + 32 + c0 + 4);                         \
  }

  LOADG(hiA[0], tiA[0]);

  const f32x4 zz = {0.f, 0.f, 0.f, 0.f};

  #pragma unroll 2
  for (int k = 0; k < 8; ++k) {
    const int p = k & 1;
    const int ri_cur = riA[p];

    // attention logit from live f32 gather regs (waits on gathers of k)
    float ap = dot4(gh0, *(const f32x4*)&awlds[c0]) +
               dot4(gh1, *(const f32x4*)&awlds[c0 + 4]) +
               dot4(gh2, *(const f32x4*)&awlds[32 + c0]) +
               dot4(gh3, *(const f32x4*)&awlds[32 + c0 + 4]) +
               dot4(gt0, *(const f32x4*)&awlds[128 + c0]) +
               dot4(gt1, *(const f32x4*)&awlds[128 + c0 + 4]) +
               dot4(gt2, *(const f32x4*)&awlds[160 + c0]) +
               dot4(gt3, *(const f32x4*)&awlds[160 + c0 + 4]);

    // pack to bf16 fragments (frees gather regs)
    const sv8 ha0 = pack8(gh0, gh1), ha1 = pack8(gh2, gh3);
    const sv8 ta0 = pack8(gt0, gt1), ta1 = pack8(gt2, gt3);

    // issue chunk k+1's gathers + chunk k+2's indices NOW
    if (k < 7) LOADG(hiA[p ^ 1], tiA[p ^ 1]);
    if (k < 6) {
      hiA[p] = heads[(size_t)(cb + k + 2) * 16 + fr];
      tiA[p] = tails[(size_t)(cb + k + 2) * 16 + fr];
      riA[p] = rels[(size_t)(cb + k + 2) * 16 + fr];
    }

    ap += __shfl_xor(ap, 16);
    ap += __shfl_xor(ap, 32);
    const float e_own = __expf(fast_sigmoid(ap + rlds[ri_cur] + ab0));
    float se = e_own;
    se += __shfl_xor(se, 1);
    se += __shfl_xor(se, 2);
    se += __shfl_xor(se, 4);
    se += __shfl_xor(se, 8);

    // GEMM1: h1 = tanh(H @ W_ih^T + bsum)
    f32x4 acc[4] = {zz, zz, zz, zz};
    #pragma unroll
    for (int nt = 0; nt < 4; ++nt)
      acc[nt] = MFMA(ha0, *(const sv8*)&wlds[0][nt * 2][lane][0], acc[nt]);
    #pragma unroll
    for (int nt = 0; nt < 4; ++nt)
      acc[nt] = MFMA(ha1, *(const sv8*)&wlds[0][nt * 2 + 1][lane][0], acc[nt]);
    #pragma unroll
    for (int nt = 0; nt < 4; ++nt)
      #pragma unroll
      for (int r = 0; r < 4; ++r)
        h1s[w][((fg << 2) + r) * 72 + nt * 16 + fr] =
            f2bfc(fast_tanh(acc[nt][r] + bsum[nt]));

    f32x4 ev;
    #pragma unroll
    for (int r = 0; r < 4; ++r) ev[r] = __shfl(e_own, (fg << 2) + r);

    // GEMM2: h2pre = TL @ W_ih^T + H1 @ W_hh^T (same-wave LDS, lgkm only)
    f32x4 acc2[4] = {zz, zz, zz, zz};
    #pragma unroll
    for (int nt = 0; nt < 4; ++nt)
      acc2[nt] = MFMA(ta0, *(const sv8*)&wlds[0][nt * 2][lane][0], acc2[nt]);
    #pragma unroll
    for (int nt = 0; nt < 4; ++nt)
      acc2[nt] = MFMA(ta1, *(const sv8*)&wlds[0][nt * 2 + 1][lane][0], acc2[nt]);
    const sv8 a1 = *(const sv8*)&h1s[w][fr * 72 + c0];
    const sv8 a2 = *(const sv8*)&h1s[w][fr * 72 + 32 + c0];
    #pragma unroll
    for (int nt = 0; nt < 4; ++nt)
      acc2[nt] = MFMA(a1, *(const sv8*)&wlds[1][nt * 2][lane][0], acc2[nt]);
    #pragma unroll
    for (int nt = 0; nt < 4; ++nt)
      acc2[nt] = MFMA(a2, *(const sv8*)&wlds[1][nt * 2 + 1][lane][0], acc2[nt]);

    // e-weighted column sums over this chunk's 16 rows
    float o4[4];
    #pragma unroll
    for (int nt = 0; nt < 4; ++nt) {
      float s = ev.x * fast_tanh(acc2[nt][0] + bsum[nt]) +
                ev.y * fast_tanh(acc2[nt][1] + bsum[nt]) +
                ev.z * fast_tanh(acc2[nt][2] + bsum[nt]) +
                ev.w * fast_tanh(acc2[nt][3] + bsum[nt]);
      s += __shfl_xor(s, 16);
      s += __shfl_xor(s, 32);
      o4[nt] = s;
    }
    // transpose to lane-linear and store partials for this chunk
    const float r0 = __shfl(o4[0], fr);
    const float r1 = __shfl(o4[1], fr);
    const float r2 = __shfl(o4[2], fr);
    const float r3 = __shfl(o4[3], fr);
    const float oval = (fg == 0) ? r0 : (fg == 1) ? r1 : (fg == 2) ? r2 : r3;
    owp[(size_t)(cb + k) * 64 + lane] = oval;
    if (lane == 0) sep[cb + k] = se;
  }
#undef LOADG
}

// ---------------------------------------------------------------------------
// Phase B: NCF head; combines the 8 per-chunk partials per batch row.
// ---------------------------------------------------------------------------
__global__ __launch_bounds__(256) void ncfg_head(
    const float* __restrict__ owp, const float* __restrict__ sep,
    const float* __restrict__ emb, const int* __restrict__ items,
    const float* __restrict__ l1_w, const float* __restrict__ l1_b,
    const float* __restrict__ l2_w, const float* __restrict__ l2_b,
    const float* __restrict__ l3_w, const float* __restrict__ l3_b,
    const float* __restrict__ lin_w, const float* __restrict__ lin_b,
    float* __restrict__ out) {
  const int wv = threadIdx.x >> 6;
  const int i = threadIdx.x & 63;
  const int b = blockIdx.x * 4 + wv;

  __shared__ float ui[4][128];
  __shared__ float yy[4][64];

  float u0 = 0.f, u1 = 0.f, s0 = 0.f, s1 = 0.f;
  #pragma unroll
  for (int s = 0; s < 4; ++s) {
    u0 += owp[(size_t)(b * 4 + s) * 64 + i];
    u1 += owp[(size_t)((B_SZ + b) * 4 + s) * 64 + i];
    s0 += sep[b * 4 + s];
    s1 += sep[(B_SZ + b) * 4 + s];
  }
  const float ue = u0 * __builtin_amdgcn_rcpf(s0) +
                   u1 * __builtin_amdgcn_rcpf(s1);
  const float ie = emb[(size_t)items[b] * 64 + i];
  ui[wv][i] = ue;
  ui[wv][64 + i] = ie;
  __syncthreads();

  float acc = l1_b[i];
  {
    const float* wr = l1_w + i * 128;
    #pragma unroll
    for (int j = 0; j < 128; j += 4) {
      const f32x4 wvv = *(const f32x4*)(wr + j);
      const f32x4 uv = *(const f32x4*)&ui[wv][j];
      acc += wvv.x * uv.x + wvv.y * uv.y + wvv.z * uv.z + wvv.w * uv.w;
    }
  }
  float y = fmaxf(acc, 0.f);
  yy[wv][i] = y;
  __syncthreads();

  acc = l2_b[i];
  {
    const float* wr = l2_w + i * 64;
    #pragma unroll
    for (int j = 0; j < 64; j += 4) {
      const f32x4 wvv = *(const f32x4*)(wr + j);
      const f32x4 uv = *(const f32x4*)&yy[wv][j];
      acc += wvv.x * uv.x + wvv.y * uv.y + wvv.z * uv.z + wvv.w * uv.w;
    }
  }
  y = fmaxf(acc, 0.f);
  __syncthreads();
  yy[wv][i] = y;
  __syncthreads();

  acc = l3_b[i];
  {
    const float* wr = l3_w + i * 64;
    #pragma unroll
    for (int j = 0; j < 64; j += 4) {
      const f32x4 wvv = *(const f32x4*)(wr + j);
      const f32x4 uv = *(const f32x4*)&yy[wv][j];
      acc += wvv.x * uv.x + wvv.y * uv.y + wvv.z * uv.z + wvv.w * uv.w;
    }
  }
  const float y1 = fast_sigmoid(acc);
  const float y2 = ue * ie;

  float part = y1 * lin_w[i] + y2 * lin_w[64 + i];
  #pragma unroll
  for (int m = 1; m < 64; m <<= 1) part += __shfl_xor(part, m);
  if (i == 0) out[b] = fast_sigmoid(part + lin_b[0]);
}

extern "C" void kernel_launch(void* const* d_in, const int* in_sizes, int n_in,
                              void* d_out, int out_size, void* d_ws,
                              size_t ws_size, hipStream_t stream) {
  (void)in_sizes; (void)n_in; (void)out_size; (void)ws_size;
  const int* items = (const int*)d_in[0];
  const int* heads = (const int*)d_in[1];
  const int* rels = (const int*)d_in[2];
  const int* tails = (const int*)d_in[3];
  const float* emb = (const float*)d_in[4];
  const float* trf = (const float*)d_in[5];
  const float* attn_w = (const float*)d_in[6];
  const float* attn_b = (const float*)d_in[7];
  const float* W_ih = (const float*)d_in[8];
  const float* W_hh = (const float*)d_in[9];
  const float* b_ih = (const float*)d_in[10];
  const float* b_hh = (const float*)d_in[11];
  const float* l1_w = (const float*)d_in[12];
  const float* l1_b = (const float*)d_in[13];
  const float* l2_w = (const float*)d_in[14];
  const float* l2_b = (const float*)d_in[15];
  const float* l3_w = (const float*)d_in[16];
  const float* l3_b = (const float*)d_in[17];
  const float* lin_w = (const float*)d_in[18];
  const float* lin_b = (const float*)d_in[19];
  float* out = (float*)d_out;
  float* owp = (float*)d_ws;                            // [32768][64] f32 = 8 MB
  float* sep = (float*)((char*)d_ws + 8u * 1024 * 1024);  // [32768] f32

  ncfg_prep<<<dim3(1), dim3(256), 0, stream>>>(W_ih, W_hh, b_ih, b_hh, trf,
                                               attn_w);
  ncfg_neigh<<<dim3(1024), dim3(256), 0, stream>>>(
      heads, rels, tails, emb, attn_w, attn_b, owp, sep);
  ncfg_head<<<dim3(B_SZ / 4), dim3(256), 0, stream>>>(
      owp, sep, emb, items, l1_w, l1_b, l2_w, l2_b, l3_w, l3_b, lin_w, lin_b,
      out);
}

// Round 11
// 83.899 us; speedup vs baseline: 2.6535x; 2.6535x over previous
//
#include <hip/hip_runtime.h>
#include <hip/hip_bf16.h>
#include <cstdint>
#include <cstddef>

#define B_SZ 4096

typedef __attribute__((ext_vector_type(4))) float f32x4;
typedef __attribute__((ext_vector_type(8))) short sv8;
typedef __attribute__((ext_vector_type(8))) __bf16 bfv8;

// Pre-packed parameters (written by ncfg_prep, read by ncfg_neigh)
__device__ __align__(16) short g_wf[2][8][64][8];  // [mat][nt*2+kh][lane][j]
__device__ float g_bsum[64];                       // b_ih + b_hh
__device__ float g_reldot[32];                     // trf[r] . attn_w[64:128]

static __device__ __forceinline__ short f2bf(float x) {
  union { float f; unsigned u; } v; v.f = x;
  unsigned r = v.u + 0x7fffu + ((v.u >> 16) & 1u);
  return (short)(r >> 16);
}
// compiler-fused conversion (pairs -> v_cvt_pk_bf16_f32)
static __device__ __forceinline__ short f2bfc(float x) {
  return (short)__builtin_bit_cast(unsigned short, __float2bfloat16(x));
}

static __device__ __forceinline__ f32x4 MFMA(sv8 a, sv8 b, f32x4 c) {
  return __builtin_amdgcn_mfma_f32_16x16x32_bf16(
      __builtin_bit_cast(bfv8, a), __builtin_bit_cast(bfv8, b), c, 0, 0, 0);
}

static __device__ __forceinline__ float fast_sigmoid(float x) {
  return __builtin_amdgcn_rcpf(1.f + __expf(-x));
}
static __device__ __forceinline__ float fast_tanh(float x) {
  const float e = __expf(2.f * x);
  return 1.f - 2.f * __builtin_amdgcn_rcpf(e + 1.f);
}
static __device__ __forceinline__ float dot4(f32x4 a, f32x4 b) {
  return a.x * b.x + a.y * b.y + a.z * b.z + a.w * b.w;
}
static __device__ __forceinline__ sv8 pack8(f32x4 a, f32x4 b) {
  sv8 f;
  f[0] = f2bfc(a.x); f[1] = f2bfc(a.y); f[2] = f2bfc(a.z); f[3] = f2bfc(a.w);
  f[4] = f2bfc(b.x); f[5] = f2bfc(b.y); f[6] = f2bfc(b.z); f[7] = f2bfc(b.w);
  return f;
}

// ---------------------------------------------------------------------------
// Prep (grid=5): blocks 0..3 pack one W fragment per thread; block 4 folds
// biases and computes rel dots.
// ---------------------------------------------------------------------------
__global__ __launch_bounds__(256) void ncfg_prep(
    const float* __restrict__ W_ih, const float* __restrict__ W_hh,
    const float* __restrict__ b_ih, const float* __restrict__ b_hh,
    const float* __restrict__ trf, const float* __restrict__ attn_w) {
  const int bid = blockIdx.x;
  const int t = threadIdx.x;
  if (bid < 4) {
    const int q = bid * 256 + t;  // 0..1023
    const int m = q >> 9, f = (q >> 6) & 7, ln = q & 63;
    const int nt = f >> 1, kh = f & 1, fr = ln & 15, fg = ln >> 4;
    const float* W = m ? W_hh : W_ih;
    const float* src = W + (nt * 16 + fr) * 64 + kh * 32 + fg * 8;
    short* dst = &g_wf[m][f][ln][0];
    #pragma unroll
    for (int j = 0; j < 8; ++j) dst[j] = f2bf(src[j]);
  } else {
    if (t < 64) g_bsum[t] = b_ih[t] + b_hh[t];
    if (t < 32) {
      float s = 0.f;
      #pragma unroll 8
      for (int c = 0; c < 64; ++c) s += trf[t * 64 + c] * attn_w[64 + c];
      g_reldot[t] = s;
    }
  }
}

// ---------------------------------------------------------------------------
// Phase A: block = (b,layer); 4 independent waves x 16 rows; W in LDS;
// VALU logits over live gather regs; LDS 26.5 KB, 6 blocks/CU target.
// ---------------------------------------------------------------------------
__global__ __launch_bounds__(256, 6) void ncfg_neigh(
    const int* __restrict__ heads, const int* __restrict__ rels,
    const int* __restrict__ tails, const float* __restrict__ emb,
    const float* __restrict__ attn_w, const float* __restrict__ attn_b,
    float* __restrict__ opart) {
  const int t = threadIdx.x;
  const int lane = t & 63;
  const int w = t >> 6;
  const int fr = lane & 15;
  const int fg = lane >> 4;
  const int c0 = fg * 8;

  __shared__ __align__(16) short wlds[2][8][64][8];  // 16 KB  W fragments
  __shared__ __align__(16) float awlds[192];         // 768 B  attn vector
  __shared__ float rlds[32];                         // 128 B  reldot
  __shared__ __align__(16) short h1s[4][16 * 72];    // 9 KB   per-wave h1
  // ow[w][0..63] and sew[w] are aliased into h1s[w] after GEMM2 (h1s dead)

  const size_t ibase = (size_t)blockIdx.x * 64;      // item = layer*B + b

  // (1) idx loads — head of the dependent chain
  const int hi = heads[ibase + (w << 4) + fr];
  const int ti = tails[ibase + (w << 4) + fr];
  const int ri = rels[ibase + (w << 4) + fr];

  // (2) stage weights / attn / reldot into LDS (L2-hot, independent of idx)
  {
    const f32x4* s1 = (const f32x4*)&g_wf[0][0][0][0];  // 1024 x 16B
    f32x4* d1 = (f32x4*)&wlds[0][0][0][0];
    #pragma unroll
    for (int i = 0; i < 4; ++i) d1[t + i * 256] = s1[t + i * 256];
    if (t < 48) ((f32x4*)awlds)[t] = ((const f32x4*)attn_w)[t];
    if (t < 8) ((f32x4*)rlds)[t] = ((const f32x4*)g_reldot)[t];
  }

  // (3) scalar params
  float bsum[4];
  #pragma unroll
  for (int nt = 0; nt < 4; ++nt) bsum[nt] = g_bsum[nt * 16 + fr];
  const float ab0 = attn_b[0];

  // (4) 8 embedding gathers — issued before the barrier
  const float* hr = emb + (size_t)hi * 64;
  const float* tr = emb + (size_t)ti * 64;
  const f32x4 h0 = *(const f32x4*)(hr + c0);
  const f32x4 h1 = *(const f32x4*)(hr + c0 + 4);
  const f32x4 h2 = *(const f32x4*)(hr + 32 + c0);
  const f32x4 h3 = *(const f32x4*)(hr + 32 + c0 + 4);
  const f32x4 t0 = *(const f32x4*)(tr + c0);
  const f32x4 t1 = *(const f32x4*)(tr + c0 + 4);
  const f32x4 t2 = *(const f32x4*)(tr + 32 + c0);
  const f32x4 t3 = *(const f32x4*)(tr + 32 + c0 + 4);

  __syncthreads();  // staging + loads complete

  // attention logit: VALU dot over live f32 regs, attn vector from LDS
  float ap = dot4(h0, *(const f32x4*)&awlds[c0]) +
             dot4(h1, *(const f32x4*)&awlds[c0 + 4]) +
             dot4(h2, *(const f32x4*)&awlds[32 + c0]) +
             dot4(h3, *(const f32x4*)&awlds[32 + c0 + 4]) +
             dot4(t0, *(const f32x4*)&awlds[128 + c0]) +
             dot4(t1, *(const f32x4*)&awlds[128 + c0 + 4]) +
             dot4(t2, *(const f32x4*)&awlds[160 + c0]) +
             dot4(t3, *(const f32x4*)&awlds[160 + c0 + 4]);
  ap += __shfl_xor(ap, 16);
  ap += __shfl_xor(ap, 32);  // full row dot, replicated over fg

  const float e_own = __expf(fast_sigmoid(ap + rlds[ri] + ab0));
  float se = e_own;
  se += __shfl_xor(se, 1);
  se += __shfl_xor(se, 2);
  se += __shfl_xor(se, 4);
  se += __shfl_xor(se, 8);   // sum over this wave's 16 rows (replicated)

  // bf16 A-fragments (frees the f32 gather regs)
  const sv8 ha0 = pack8(h0, h1), ha1 = pack8(h2, h3);
  const sv8 ta0 = pack8(t0, t1), ta1 = pack8(t2, t3);

  const f32x4 zz = {0.f, 0.f, 0.f, 0.f};

  // GEMM1: h1 = tanh(H @ W_ih^T + bsum)
  f32x4 acc[4] = {zz, zz, zz, zz};
  #pragma unroll
  for (int nt = 0; nt < 4; ++nt)
    acc[nt] = MFMA(ha0, *(const sv8*)&wlds[0][nt * 2][lane][0], acc[nt]);
  #pragma unroll
  for (int nt = 0; nt < 4; ++nt)
    acc[nt] = MFMA(ha1, *(const sv8*)&wlds[0][nt * 2 + 1][lane][0], acc[nt]);
  #pragma unroll
  for (int nt = 0; nt < 4; ++nt)
    #pragma unroll
    for (int r = 0; r < 4; ++r)
      h1s[w][((fg << 2) + r) * 72 + nt * 16 + fr] =
          f2bfc(fast_tanh(acc[nt][r] + bsum[nt]));

  // e for D-layout rows fg*4+r
  f32x4 ev;
  #pragma unroll
  for (int r = 0; r < 4; ++r) ev[r] = __shfl(e_own, (fg << 2) + r);

  // GEMM2: h2pre = TL @ W_ih^T + H1 @ W_hh^T (same-wave LDS transpose)
  f32x4 acc2[4] = {zz, zz, zz, zz};
  #pragma unroll
  for (int nt = 0; nt < 4; ++nt)
    acc2[nt] = MFMA(ta0, *(const sv8*)&wlds[0][nt * 2][lane][0], acc2[nt]);
  #pragma unroll
  for (int nt = 0; nt < 4; ++nt)
    acc2[nt] = MFMA(ta1, *(const sv8*)&wlds[0][nt * 2 + 1][lane][0], acc2[nt]);
  const sv8 a1 = *(const sv8*)&h1s[w][fr * 72 + c0];
  const sv8 a2 = *(const sv8*)&h1s[w][fr * 72 + 32 + c0];
  #pragma unroll
  for (int nt = 0; nt < 4; ++nt)
    acc2[nt] = MFMA(a1, *(const sv8*)&wlds[1][nt * 2][lane][0], acc2[nt]);
  #pragma unroll
  for (int nt = 0; nt < 4; ++nt)
    acc2[nt] = MFMA(a2, *(const sv8*)&wlds[1][nt * 2 + 1][lane][0], acc2[nt]);

  // e-weighted column sums; partials into h1s-aliased scratch (h1s now dead)
  float* owp = (float*)&h1s[w][0];   // 64 floats (shorts 0..127)
  #pragma unroll
  for (int nt = 0; nt < 4; ++nt) {
    float s = ev.x * fast_tanh(acc2[nt][0] + bsum[nt]) +
              ev.y * fast_tanh(acc2[nt][1] + bsum[nt]) +
              ev.z * fast_tanh(acc2[nt][2] + bsum[nt]) +
              ev.w * fast_tanh(acc2[nt][3] + bsum[nt]);
    s += __shfl_xor(s, 16);
    s += __shfl_xor(s, 32);
    if (fg == 0) owp[nt * 16 + fr] = s;
  }
  if (lane == 0) owp[64] = se;       // sew slot (shorts 128..129)

  __syncthreads();  // final combine barrier

  if (w == 0) {
    float o = 0.f, st = 0.f;
    #pragma unroll
    for (int q = 0; q < 4; ++q) {
      const float* p = (const float*)&h1s[q][0];
      o += p[lane];
      st += p[64];
    }
    opart[ibase + lane] = o * __builtin_amdgcn_rcpf(st);
  }
}

// ---------------------------------------------------------------------------
// Phase B: NCF head. 4 batch rows per block (1 wave each).
// ---------------------------------------------------------------------------
__global__ __launch_bounds__(256) void ncfg_head(
    const float* __restrict__ opart, const float* __restrict__ emb,
    const int* __restrict__ items, const float* __restrict__ l1_w,
    const float* __restrict__ l1_b, const float* __restrict__ l2_w,
    const float* __restrict__ l2_b, const float* __restrict__ l3_w,
    const float* __restrict__ l3_b, const float* __restrict__ lin_w,
    const float* __restrict__ lin_b, float* __restrict__ out) {
  const int wv = threadIdx.x >> 6;
  const int i = threadIdx.x & 63;
  const int b = blockIdx.x * 4 + wv;

  __shared__ float ui[4][128];
  __shared__ float yy[4][64];

  const float ue = opart[(size_t)b * 64 + i] +
                   opart[((size_t)B_SZ + b) * 64 + i];
  const float ie = emb[(size_t)items[b] * 64 + i];
  ui[wv][i] = ue;
  ui[wv][64 + i] = ie;
  __syncthreads();

  float acc = l1_b[i];
  {
    const float* wr = l1_w + i * 128;
    #pragma unroll
    for (int j = 0; j < 128; j += 4) {
      const f32x4 wvv = *(const f32x4*)(wr + j);
      const f32x4 uv = *(const f32x4*)&ui[wv][j];
      acc += wvv.x * uv.x + wvv.y * uv.y + wvv.z * uv.z + wvv.w * uv.w;
    }
  }
  float y = fmaxf(acc, 0.f);
  yy[wv][i] = y;
  __syncthreads();

  acc = l2_b[i];
  {
    const float* wr = l2_w + i * 64;
    #pragma unroll
    for (int j = 0; j < 64; j += 4) {
      const f32x4 wvv = *(const f32x4*)(wr + j);
      const f32x4 uv = *(const f32x4*)&yy[wv][j];
      acc += wvv.x * uv.x + wvv.y * uv.y + wvv.z * uv.z + wvv.w * uv.w;
    }
  }
  y = fmaxf(acc, 0.f);
  __syncthreads();
  yy[wv][i] = y;
  __syncthreads();

  acc = l3_b[i];
  {
    const float* wr = l3_w + i * 64;
    #pragma unroll
    for (int j = 0; j < 64; j += 4) {
      const f32x4 wvv = *(const f32x4*)(wr + j);
      const f32x4 uv = *(const f32x4*)&yy[wv][j];
      acc += wvv.x * uv.x + wvv.y * uv.y + wvv.z * uv.z + wvv.w * uv.w;
    }
  }
  const float y1 = fast_sigmoid(acc);
  const float y2 = ue * ie;

  float part = y1 * lin_w[i] + y2 * lin_w[64 + i];
  #pragma unroll
  for (int m = 1; m < 64; m <<= 1) part += __shfl_xor(part, m);
  if (i == 0) out[b] = fast_sigmoid(part + lin_b[0]);
}

extern "C" void kernel_launch(void* const* d_in, const int* in_sizes, int n_in,
                              void* d_out, int out_size, void* d_ws,
                              size_t ws_size, hipStream_t stream) {
  (void)in_sizes; (void)n_in; (void)out_size; (void)ws_size;
  const int* items = (const int*)d_in[0];
  const int* heads = (const int*)d_in[1];
  const int* rels = (const int*)d_in[2];
  const int* tails = (const int*)d_in[3];
  const float* emb = (const float*)d_in[4];
  const float* trf = (const float*)d_in[5];
  const float* attn_w = (const float*)d_in[6];
  const float* attn_b = (const float*)d_in[7];
  const float* W_ih = (const float*)d_in[8];
  const float* W_hh = (const float*)d_in[9];
  const float* b_ih = (const float*)d_in[10];
  const float* b_hh = (const float*)d_in[11];
  const float* l1_w = (const float*)d_in[12];
  const float* l1_b = (const float*)d_in[13];
  const float* l2_w = (const float*)d_in[14];
  const float* l2_b = (const float*)d_in[15];
  const float* l3_w = (const float*)d_in[16];
  const float* l3_b = (const float*)d_in[17];
  const float* lin_w = (const float*)d_in[18];
  const float* lin_b = (const float*)d_in[19];
  float* out = (float*)d_out;
  float* opart = (float*)d_ws;  // [L=2][B=4096][64] f32 = 2 MB

  ncfg_prep<<<dim3(5), dim3(256), 0, stream>>>(W_ih, W_hh, b_ih, b_hh, trf,
                                               attn_w);
  ncfg_neigh<<<dim3(2 * B_SZ), dim3(256), 0, stream>>>(
      heads, rels, tails, emb, attn_w, attn_b, opart);
  ncfg_head<<<dim3(B_SZ / 4), dim3(256), 0, stream>>>(
      opart, emb, items, l1_w, l1_b, l2_w, l2_b, l3_w, l3_b, lin_w, lin_b,
      out);
}